// Round 11
// baseline (491.729 us; speedup 1.0000x reference)
//
#include <hip/hip_runtime.h>
#include <math.h>

#define LAM 9.0f
#define EPSF 1e-8f

typedef unsigned int uint;
typedef unsigned short ushort_t;
typedef __attribute__((ext_vector_type(8))) short short8;
typedef __attribute__((ext_vector_type(4))) float float4v;

// ws layout (floats)
#define OFF_MMU 0                       // ushort planes: [hi 16384][lo 16384] per matrix
#define OFF_MLV (512*32)
#define OFF_M1  (2*512*32)
#define OFF_S   (3*512*32)              // 49152 : s[c][l] (64*32)
#define OFF_W   (OFF_S + 64*32)         // 51200 : w[b][c] (64*64)
#define OFF_QN  (OFF_W + 64*64)         // 55296 : qn[c][l][f] (64*32*32)
#define OFF_TS  (OFF_QN + 64*32*32)     // 120832: tnode_s[c][b][l][f] (64*64*32*32)
#define OFF_ATTN (OFF_TS + 64*64*32*32) // attn [2304][NW]
#define OFF_CVT  (OFF_ATTN + 2304*2048) // hi/lo bf16 arrays (ushort); REUSED by imgT after k2a

#define N_IMG_EL 2359296                // 2304*1024
#define N_CAP_EL 2097152                // 2048*1024
#define IMGT_EL  (64*1024*64)           // imgT per plane (ushorts)

__device__ __forceinline__ ushort_t bf16_rne(float x) {
    uint u = __float_as_uint(x);
    uint r = (u + 0x7fffu + ((u >> 16) & 1u)) >> 16;
    return (ushort_t)r;
}
__device__ __forceinline__ float bf16_f(ushort_t h) {
    return __uint_as_float(((uint)h) << 16);
}
__device__ __forceinline__ uint pack2(ushort_t a, ushort_t b) {
    return (uint)a | ((uint)b << 16);
}

// ---------------- kcvt: split images+captions into hi/lo bf16 (Markidis) ----------------
__global__ __launch_bounds__(256) void kcvt(const float* __restrict__ img,
                                            const float* __restrict__ cap,
                                            ushort_t* __restrict__ dst) {
    size_t i = (size_t)blockIdx.x * 256 + threadIdx.x;   // float4 index
    const float* src;
    ushort_t *H, *L;
    size_t base;
    if (i < (N_IMG_EL / 4)) {
        src = img; H = dst; L = dst + N_IMG_EL; base = i * 4;
    } else {
        src = cap; H = dst + 2 * (size_t)N_IMG_EL; L = H + N_CAP_EL; base = (i - N_IMG_EL / 4) * 4;
    }
    float4 v = *(const float4*)(src + base);
    float x[4] = {v.x, v.y, v.z, v.w};
    ushort_t hh[4], ll[4];
    #pragma unroll
    for (int j = 0; j < 4; j++) {
        hh[j] = bf16_rne(x[j]);
        ll[j] = bf16_rne(x[j] - bf16_f(hh[j]));
    }
    *(uint2*)(H + base) = make_uint2(pack2(hh[0], hh[1]), pack2(hh[2], hh[3]));
    *(uint2*)(L + base) = make_uint2(pack2(ll[0], ll[1]), pack2(ll[2], ll[3]));
}

// ---------------- kcvt2: build imgT[b][e][64 r-pad] hi/lo (overwrites OFF_CVT after k2a) --------
__global__ __launch_bounds__(256) void kcvt2(const float* __restrict__ img,
                                             ushort_t* __restrict__ dstH) {
    int b = blockIdx.x >> 3, ec = blockIdx.x & 7;       // e0 = ec*128
    __shared__ float S[36][132];
    int t = threadIdx.x;
    for (int i = t; i < 1152; i += 256) {               // img[b][r][e0..e0+127]
        int r = i >> 5, q = i & 31;
        *(float4*)&S[r][q * 4] = *(const float4*)(img + ((size_t)b * 36 + r) * 1024 + ec * 128 + q * 4);
    }
    __syncthreads();
    ushort_t* H = dstH + ((size_t)b * 1024 + ec * 128) * 64;
    ushort_t* L = dstH + (size_t)IMGT_EL + ((size_t)b * 1024 + ec * 128) * 64;
    for (int i = t; i < 1024; i += 256) {               // 128 e x 8 r-octets
        int e = i >> 3, rg = i & 7;
        ushort_t hh[8], ll[8];
        #pragma unroll
        for (int j = 0; j < 8; j++) {
            int r = rg * 8 + j;
            float v = (r < 36) ? S[r][e] : 0.f;
            hh[j] = bf16_rne(v);
            ll[j] = bf16_rne(v - bf16_f(hh[j]));
        }
        uint4 uh, ul;
        uh.x = pack2(hh[0], hh[1]); uh.y = pack2(hh[2], hh[3]);
        uh.z = pack2(hh[4], hh[5]); uh.w = pack2(hh[6], hh[7]);
        ul.x = pack2(ll[0], ll[1]); ul.y = pack2(ll[2], ll[3]);
        ul.z = pack2(ll[4], ll[5]); ul.w = pack2(ll[6], ll[7]);
        *(uint4*)(H + (size_t)e * 64 + rg * 8) = uh;
        *(uint4*)(L + (size_t)e * 64 + rg * 8) = ul;
    }
}

// ---------------- k2a_mfma: attn = IMG(2304x1024) @ CAP^T via split-bf16 MFMA ----------------
__global__ __launch_bounds__(256) void k2a_mfma(const ushort_t* __restrict__ cvt,
                                                float* __restrict__ C) {
    const ushort_t* imgH = cvt;
    const ushort_t* imgL = cvt + N_IMG_EL;
    const ushort_t* capH = cvt + 2 * (size_t)N_IMG_EL;
    const ushort_t* capL = capH + N_CAP_EL;
    __shared__ ushort_t Ah[128][32], Al[128][32], Bh[64][32], Bl[64][32];
    int t = threadIdx.x, w = t >> 6, lane = t & 63;
    int quad = lane >> 4, mn = lane & 15;
    int m0 = blockIdx.x * 128, n0 = blockIdx.y * 64;
    float4v acc[2][4];
    #pragma unroll
    for (int i = 0; i < 2; i++)
        #pragma unroll
        for (int j = 0; j < 4; j++) acc[i][j] = (float4v){0.f, 0.f, 0.f, 0.f};

    for (int kc = 0; kc < 32; kc++) {
        #pragma unroll
        for (int j = 0; j < 6; j++) {
            int ch = t + j * 256;                   // 1536 16B chunks
            if (ch < 512) {
                int row = ch >> 2, seg = ch & 3;
                *(uint4*)&Ah[row][seg * 8] = *(const uint4*)(imgH + (size_t)(m0 + row) * 1024 + kc * 32 + seg * 8);
            } else if (ch < 1024) {
                int r2 = ch - 512, row = r2 >> 2, seg = r2 & 3;
                *(uint4*)&Al[row][seg * 8] = *(const uint4*)(imgL + (size_t)(m0 + row) * 1024 + kc * 32 + seg * 8);
            } else if (ch < 1280) {
                int r2 = ch - 1024, row = r2 >> 2, seg = r2 & 3;
                *(uint4*)&Bh[row][seg * 8] = *(const uint4*)(capH + (size_t)(n0 + row) * 1024 + kc * 32 + seg * 8);
            } else {
                int r2 = ch - 1280, row = r2 >> 2, seg = r2 & 3;
                *(uint4*)&Bl[row][seg * 8] = *(const uint4*)(capL + (size_t)(n0 + row) * 1024 + kc * 32 + seg * 8);
            }
        }
        __syncthreads();
        short8 ah[2], al[2];
        #pragma unroll
        for (int tm = 0; tm < 2; tm++) {
            ah[tm] = *(short8*)&Ah[w * 32 + tm * 16 + mn][quad * 8];
            al[tm] = *(short8*)&Al[w * 32 + tm * 16 + mn][quad * 8];
        }
        #pragma unroll
        for (int nt = 0; nt < 4; nt++) {
            short8 bh = *(short8*)&Bh[nt * 16 + mn][quad * 8];
            short8 bl = *(short8*)&Bl[nt * 16 + mn][quad * 8];
            #pragma unroll
            for (int tm = 0; tm < 2; tm++) {
                acc[tm][nt] = __builtin_amdgcn_mfma_f32_16x16x32_bf16(ah[tm], bh, acc[tm][nt], 0, 0, 0);
                acc[tm][nt] = __builtin_amdgcn_mfma_f32_16x16x32_bf16(ah[tm], bl, acc[tm][nt], 0, 0, 0);
                acc[tm][nt] = __builtin_amdgcn_mfma_f32_16x16x32_bf16(al[tm], bh, acc[tm][nt], 0, 0, 0);
            }
        }
        __syncthreads();
    }
    #pragma unroll
    for (int tm = 0; tm < 2; tm++)
        #pragma unroll
        for (int nt = 0; nt < 4; nt++)
            #pragma unroll
            for (int r = 0; r < 4; r++) {
                int mrow = m0 + w * 32 + tm * 16 + quad * 4 + r;
                int ncol = n0 + nt * 16 + mn;
                C[(size_t)mrow * 2048 + ncol] = acc[tm][nt][r];
            }
}

// ---------------- kpre: M_X = W_X @ W_gc (512x32); emit bf16 hi/lo planes ----------------
__global__ __launch_bounds__(256) void kpre(const float* __restrict__ Wmu,
                                            const float* __restrict__ Wlv,
                                            const float* __restrict__ W1,
                                            const float* __restrict__ Wgc,
                                            float* __restrict__ ws) {
    int m = blockIdx.x >> 6;            // 0..2
    int hg = blockIdx.x & 63;           // 0..63
    int h0 = hg * 8;
    const float* W = (m == 0) ? Wmu : (m == 1) ? Wlv : W1;
    __shared__ float Gs[64][32];
    __shared__ float Ws[8][68];
    int t = threadIdx.x;
    int h = t >> 5, f = t & 31;
    float acc = 0.f;
    for (int kc = 0; kc < 8; kc++) {
        for (int i = t; i < 512; i += 256) {
            int row = i >> 3, c4 = i & 7;
            *(float4*)&Gs[row][c4 * 4] = *(const float4*)(Wgc + (kc * 64 + row) * 32 + c4 * 4);
        }
        if (t < 128) {
            int hh = t >> 4, c4 = t & 15;
            *(float4*)&Ws[hh][c4 * 4] = *(const float4*)(W + (size_t)(h0 + hh) * 512 + kc * 64 + c4 * 4);
        }
        __syncthreads();
        #pragma unroll 4
        for (int k = 0; k < 64; k++) acc += Ws[h][k] * Gs[k][f];
        __syncthreads();
    }
    ushort_t* Mb = (ushort_t*)ws + m * 32768;       // [hi 16384][lo 16384]
    ushort_t hi = bf16_rne(acc);
    ushort_t lo = bf16_rne(acc - bf16_f(hi));
    Mb[(h0 + h) * 32 + f] = hi;
    Mb[16384 + (h0 + h) * 32 + f] = lo;
}

// ---------------- k1: per caption: words_sim -> adj -> s[c][l] ; + qn[c][l][f] ----------------
__global__ __launch_bounds__(256) void k1(const float* __restrict__ captions,
                                          const int* __restrict__ depends,
                                          float* __restrict__ ws) {
    int c = blockIdx.x;
    __shared__ float caps[32][65];
    __shared__ float G[32][33];
    __shared__ float adj[32][33];
    int t = threadIdx.x;
    int l2 = t & 31, l1_0 = t >> 5;
    float acc[4] = {0.f, 0.f, 0.f, 0.f};
    const float* cap = captions + (size_t)c * 32 * 1024;

    for (int kc = 0; kc < 16; kc++) {
        for (int i = t; i < 512; i += 256) {
            int ll = i >> 4, q = i & 15;
            float4 v = *(const float4*)(cap + ll * 1024 + kc * 64 + q * 4);
            caps[ll][q * 4 + 0] = v.x; caps[ll][q * 4 + 1] = v.y;
            caps[ll][q * 4 + 2] = v.z; caps[ll][q * 4 + 3] = v.w;
        }
        __syncthreads();
        #pragma unroll 4
        for (int k = 0; k < 64; k++) {
            float cv = caps[l2][k];
            #pragma unroll
            for (int i = 0; i < 4; i++) acc[i] += caps[l1_0 + 8 * i][k] * cv;
        }
        __syncthreads();
    }
    #pragma unroll
    for (int i = 0; i < 4; i++) G[l1_0 + 8 * i][l2] = acc[i];
    for (int i = t; i < 32 * 33; i += 256) ((float*)adj)[i] = 0.f;
    __syncthreads();

    if (t < 32) {
        float mx = -1e30f;
        for (int n = 0; n < 32; n++) mx = fmaxf(mx, LAM * G[t][n]);
        float sum = 0.f;
        for (int n = 0; n < 32; n++) { float p = __expf(LAM * G[t][n] - mx); G[t][n] = p; sum += p; }
        float inv = 1.f / sum;
        for (int n = 0; n < 32; n++) G[t][n] *= inv;
    }
    __syncthreads();
    if (t >= 1 && t < 30) {
        int d0 = depends[c * 60 + t * 2 + 0];
        int d1 = depends[c * 60 + t * 2 + 1];
        adj[d0][d1] = 1.f;
        adj[d1][d0] = 1.f;
    }
    __syncthreads();
    if (t < 32) adj[t][t] += 1.f;
    __syncthreads();
    if (t < 32) {
        float ss = 0.f, sw = 0.f;
        for (int n = 0; n < 32; n++) { float mm = adj[t][n] * G[t][n]; ss += mm * mm; }
        float inv = 1.f / (sqrtf(ss) + EPSF);
        for (int n = 0; n < 32; n++) sw += adj[t][n] * G[t][n] * adj[t][n];
        ws[OFF_S + c * 32 + t] = sw * inv;
    }
    for (int p = t; p < 1024; p += 256) {
        int l = p >> 5, f = p & 31;
        const float* cp = cap + (size_t)l * 1024 + f * 32;
        float q2 = 0.f;
        #pragma unroll
        for (int q = 0; q < 8; q++) {
            float4 v = *(const float4*)(cp + q * 4);
            q2 += v.x * v.x + v.y * v.y + v.z * v.z + v.w * v.w;
        }
        ws[OFF_QN + c * 1024 + p] = sqrtf(q2);
    }
}

// ---------------- k2a (fp32 fallback) ----------------
__global__ __launch_bounds__(256) void k2a(const float* __restrict__ A,
                                           const float* __restrict__ Bm,
                                           float* __restrict__ C,
                                           int n0, int NW) {
    __shared__ float As[16][132];
    __shared__ float Bs[16][68];
    int m0 = blockIdx.x * 128;
    int nb0 = n0 + blockIdx.y * 64;
    int t = threadIdx.x;
    int tm = t >> 4, tn = t & 15;
    float acc[8][4] = {};
    for (int kc = 0; kc < 64; kc++) {
        #pragma unroll
        for (int j = 0; j < 2; j++) {
            int idx = t + j * 256;
            int row = idx >> 2, kq = idx & 3;
            float4 v = *(const float4*)(A + (size_t)(m0 + row) * 1024 + kc * 16 + kq * 4);
            As[kq * 4 + 0][row] = v.x; As[kq * 4 + 1][row] = v.y;
            As[kq * 4 + 2][row] = v.z; As[kq * 4 + 3][row] = v.w;
        }
        {
            int row = t >> 2, kq = t & 3;
            float4 v = *(const float4*)(Bm + (size_t)(nb0 + row) * 1024 + kc * 16 + kq * 4);
            Bs[kq * 4 + 0][row] = v.x; Bs[kq * 4 + 1][row] = v.y;
            Bs[kq * 4 + 2][row] = v.z; Bs[kq * 4 + 3][row] = v.w;
        }
        __syncthreads();
        #pragma unroll
        for (int kk = 0; kk < 16; kk++) {
            float a0[4], a1[4], bb[4];
            *(float4*)a0 = *(float4*)&As[kk][tm * 8];
            *(float4*)a1 = *(float4*)&As[kk][tm * 8 + 4];
            *(float4*)bb = *(float4*)&Bs[kk][tn * 4];
            #pragma unroll
            for (int i = 0; i < 4; i++)
                #pragma unroll
                for (int j2 = 0; j2 < 4; j2++) {
                    acc[i][j2]     += a0[i] * bb[j2];
                    acc[i + 4][j2] += a1[i] * bb[j2];
                }
        }
        __syncthreads();
    }
    int cw0 = nb0 - n0 + tn * 4;
    #pragma unroll
    for (int i = 0; i < 8; i++) {
        float4 v = make_float4(acc[i][0], acc[i][1], acc[i][2], acc[i][3]);
        *(float4*)(C + (size_t)(m0 + tm * 8 + i) * NW + cw0) = v;
    }
}

// ---------------- k2bm v4: per (c,b) one wave; NO barriers in f-loop (loads pipeline freely) ----
// cap read direct from global (16 fully-used 64B lines per load); tnode staged in LDS, burst out.
__global__ __launch_bounds__(64) void k2bm(const ushort_t* __restrict__ imgT,
                                           const float* __restrict__ captions,
                                           const float* __restrict__ attn,
                                           const float* __restrict__ ws,
                                           float* __restrict__ ts_out) {
    int c = blockIdx.x >> 6, b = blockIdx.x & 63;
    __shared__ union {
        float A[36][36];                        // attn tile [r][l] -> asmx (phase 1)
        float T[32][36];                        // tnode tile [l][f]      (phase 2)
    } u;
    int t = threadIdx.x;

    for (int i = t; i < 288; i += 64) {
        int r = i >> 3, q = i & 7;
        *(float4*)&u.A[r][q * 4] = *(const float4*)(attn + (size_t)(b * 36 + r) * 2048 + c * 32 + q * 4);
    }
    __syncthreads();
    if (t < 36) {                               // leaky + l2norm over words (per region)
        float ss = 0.f;
        #pragma unroll
        for (int l = 0; l < 32; l++) {
            float v = u.A[t][l];
            v = (v >= 0.f) ? v : 0.1f * v;
            u.A[t][l] = v; ss += v * v;
        }
        float inv = 1.f / (sqrtf(ss) + EPSF);
        #pragma unroll
        for (int l = 0; l < 32; l++) u.A[t][l] *= inv;
    }
    __syncthreads();
    if (t < 32) {                               // softmax over regions (per word), in place
        float mx = -1e30f;
        for (int r = 0; r < 36; r++) mx = fmaxf(mx, u.A[r][t]);
        mx *= LAM;
        float sum = 0.f;
        for (int r = 0; r < 36; r++) { float p = __expf(LAM * u.A[r][t] - mx); u.A[r][t] = p; sum += p; }
        float inv = 1.f / sum;
        for (int r = 0; r < 36; r++) u.A[r][t] *= inv;
    }
    __syncthreads();

    int quad = t >> 4, mn = t & 15;
    // B-frag (k=r, n=l): element j -> A[ks*32 + quad*8 + j][nt*16 + mn], split hi/lo in-register
    short8 bh[2][2], bl[2][2];
    #pragma unroll
    for (int nt = 0; nt < 2; nt++)
        #pragma unroll
        for (int ks = 0; ks < 2; ks++) {
            union { short8 v; ushort_t u8[8]; } H, L;
            #pragma unroll
            for (int j = 0; j < 8; j++) {
                int r = ks * 32 + quad * 8 + j;
                float v = (r < 36) ? u.A[r][nt * 16 + mn] : 0.f;
                ushort_t hi = bf16_rne(v);
                H.u8[j] = hi;
                L.u8[j] = bf16_rne(v - bf16_f(hi));
            }
            bh[nt][ks] = H.v;
            bl[nt][ks] = L.v;
        }
    __syncthreads();                            // A dead; union space becomes T

    const ushort_t* ibH = imgT + (size_t)b * 1024 * 64;
    const ushort_t* ibL = imgT + (size_t)IMGT_EL + (size_t)b * 1024 * 64;
    const float* cap = captions + (size_t)c * 32 * 1024;
    const float* qnp = ws + OFF_QN + c * 1024;
    float s0 = ws[OFF_S + c * 32 + mn];
    float s1 = ws[OFF_S + c * 32 + 16 + mn];

    for (int f = 0; f < 32; f++) {
        float num[2] = {0.f, 0.f}, w2a[2] = {0.f, 0.f};
        #pragma unroll
        for (int h = 0; h < 2; h++) {
            int mt = f * 2 + h;
            const ushort_t* pH = ibH + (size_t)(mt * 16 + mn) * 64 + quad * 8;
            const ushort_t* pL = ibL + (size_t)(mt * 16 + mn) * 64 + quad * 8;
            short8 ah0 = *(const short8*)pH;
            short8 ah1 = *(const short8*)(pH + 32);
            short8 al0 = *(const short8*)pL;
            short8 al1 = *(const short8*)(pL + 32);
            #pragma unroll
            for (int nt = 0; nt < 2; nt++) {
                float4v acc = (float4v){0.f, 0.f, 0.f, 0.f};
                acc = __builtin_amdgcn_mfma_f32_16x16x32_bf16(ah0, bh[nt][0], acc, 0, 0, 0);
                acc = __builtin_amdgcn_mfma_f32_16x16x32_bf16(ah0, bl[nt][0], acc, 0, 0, 0);
                acc = __builtin_amdgcn_mfma_f32_16x16x32_bf16(al0, bh[nt][0], acc, 0, 0, 0);
                acc = __builtin_amdgcn_mfma_f32_16x16x32_bf16(ah1, bh[nt][1], acc, 0, 0, 0);
                acc = __builtin_amdgcn_mfma_f32_16x16x32_bf16(ah1, bl[nt][1], acc, 0, 0, 0);
                acc = __builtin_amdgcn_mfma_f32_16x16x32_bf16(al1, bh[nt][1], acc, 0, 0, 0);
                // lane holds wctxT[e = mt*16 + quad*4 + r][l = nt*16 + mn]
                // direct global cap read: 16 x 64B fully-used lines per load, L2-resident
                float4 cv = *(const float4*)(cap + (size_t)(nt * 16 + mn) * 1024 + f * 32 + h * 16 + quad * 4);
                num[nt] += cv.x * acc[0] + cv.y * acc[1] + cv.z * acc[2] + cv.w * acc[3];
                w2a[nt] += acc[0] * acc[0] + acc[1] * acc[1] + acc[2] * acc[2] + acc[3] * acc[3];
            }
        }
        #pragma unroll
        for (int nt = 0; nt < 2; nt++) {
            float n = num[nt], w = w2a[nt];
            n += __shfl_xor(n, 16); n += __shfl_xor(n, 32);
            w += __shfl_xor(w, 16); w += __shfl_xor(w, 32);
            if (quad == 0) {
                int l = nt * 16 + mn;
                float den = fmaxf(qnp[l * 32 + f] * sqrtf(w), EPSF);
                float sv = nt ? s1 : s0;
                u.T[l][f] = (n / den) * sv;     // in-wave LDS store; no barrier needed per-f
            }
        }
    }
    __syncthreads();
    // coalesced 4KB burst: block's tnode tile is contiguous in ts_out
    float* dst = ts_out + ((size_t)c * 64 + b) * 1024;
    #pragma unroll
    for (int j = 0; j < 4; j++) {
        int id = t + j * 64;
        int l = id >> 3, q = id & 7;
        *(float4*)(dst + l * 32 + q * 4) = *(float4*)&u.T[l][q * 4];
    }
}

// ---------------- k2b (fp32 fallback, validated R4 version) ----------------
__global__ __launch_bounds__(256) void k2b(const float* __restrict__ images,
                                           const float* __restrict__ captions,
                                           const float* __restrict__ attn,
                                           const float* __restrict__ ws,
                                           float* __restrict__ ts_out,
                                           int c0, int NW) {
    int b = blockIdx.x;
    int cw = blockIdx.y;
    int ca = c0 + cw * 2;
    __shared__ float A2[2][36][36];
    __shared__ float Ims[36][256];
    __shared__ float scs[2][32];
    const float* img = images + (size_t)b * 36 * 1024;
    int t = threadIdx.x;
    int el = t & 63;
    int lg = t >> 6;

    for (int i = t; i < 576; i += 256) {
        int r = i >> 4, q = i & 15;
        float4 v = *(const float4*)(attn + (size_t)(b * 36 + r) * NW + cw * 64 + q * 4);
        *(float4*)&A2[q >> 3][r][(q & 7) * 4] = v;
    }
    __syncthreads();
    if (t < 72) {
        int ci = t >= 36, r = t - 36 * ci;
        float ss = 0.f;
        #pragma unroll
        for (int l = 0; l < 32; l++) {
            float v = A2[ci][r][l];
            v = (v >= 0.f) ? v : 0.1f * v;
            A2[ci][r][l] = v; ss += v * v;
        }
        float inv = 1.f / (sqrtf(ss) + EPSF);
        #pragma unroll
        for (int l = 0; l < 32; l++) A2[ci][r][l] *= inv;
    }
    __syncthreads();
    if (t < 64) {
        int ci = t >> 5, l = t & 31;
        float mx = -1e30f;
        for (int r = 0; r < 36; r++) mx = fmaxf(mx, A2[ci][r][l]);
        mx *= LAM;
        float sum = 0.f;
        for (int r = 0; r < 36; r++) { float p = __expf(LAM * A2[ci][r][l] - mx); A2[ci][r][l] = p; sum += p; }
        float inv = 1.f / sum;
        for (int r = 0; r < 36; r++) A2[ci][r][l] *= inv;
    } else if (t >= 128 && t < 192) {
        int i = t - 128;
        scs[i >> 5][i & 31] = ws[OFF_S + (ca + (i >> 5)) * 32 + (i & 31)];
    }
    __syncthreads();

    const float* qn = ws + OFF_QN;
    for (int g = 0; g < 4; g++) {
        for (int i = t; i < 2304; i += 256) {
            int r = i >> 6, q = i & 63;
            *(float4*)&Ims[r][q * 4] = *(const float4*)(img + (size_t)r * 1024 + g * 256 + q * 4);
        }
        __syncthreads();

        float acc[2][8][4] = {};
        #pragma unroll 2
        for (int r = 0; r < 36; r++) {
            float4 iv = *(float4*)&Ims[r][el * 4];
            float ivv[4] = {iv.x, iv.y, iv.z, iv.w};
            #pragma unroll
            for (int ci = 0; ci < 2; ci++) {
                float av[8];
                *(float4*)&av[0] = *(float4*)&A2[ci][r][lg * 8];
                *(float4*)&av[4] = *(float4*)&A2[ci][r][lg * 8 + 4];
                #pragma unroll
                for (int i = 0; i < 8; i++)
                    #pragma unroll
                    for (int e = 0; e < 4; e++)
                        acc[ci][i][e] += av[i] * ivv[e];
            }
        }

        int fb = el >> 3;
        int f = g * 8 + fb;
        #pragma unroll
        for (int ci = 0; ci < 2; ci++) {
            int c = ca + ci;
            const float* cap = captions + (size_t)c * 32 * 1024 + g * 256;
            #pragma unroll
            for (int i = 0; i < 8; i++) {
                int l = lg * 8 + i;
                float4 cv = *(const float4*)(cap + (size_t)l * 1024 + el * 4);
                float num = cv.x * acc[ci][i][0] + cv.y * acc[ci][i][1]
                          + cv.z * acc[ci][i][2] + cv.w * acc[ci][i][3];
                float w2 = acc[ci][i][0] * acc[ci][i][0] + acc[ci][i][1] * acc[ci][i][1]
                         + acc[ci][i][2] * acc[ci][i][2] + acc[ci][i][3] * acc[ci][i][3];
                num += __shfl_down(num, 4); w2 += __shfl_down(w2, 4);
                num += __shfl_down(num, 2); w2 += __shfl_down(w2, 2);
                num += __shfl_down(num, 1); w2 += __shfl_down(w2, 1);
                if ((el & 7) == 0) {
                    float den = fmaxf(qn[c * 1024 + l * 32 + f] * sqrtf(w2), EPSF);
                    ts_out[(((size_t)c * 64 + b) * 32 + l) * 32 + f] = (num / den) * scs[ci][l];
                }
            }
        }
        __syncthreads();
    }
}

// ---------------- k3 (MFMA): similarities[b][c] = mean_l W2·tanh(ts@M1^T + b1) + b2 ----------------
__global__ __launch_bounds__(256) void k3(const float* __restrict__ ts_ws,
                                          const ushort_t* __restrict__ Mb,
                                          const float* __restrict__ b1,
                                          const float* __restrict__ W2,
                                          const float* __restrict__ b2,
                                          float* __restrict__ out_sim) {
    int c = blockIdx.x >> 6, b = blockIdx.x & 63;
    __shared__ ushort_t tsh[32][32], tsl[32][32];
    __shared__ float red[4];
    int t = threadIdx.x;
    const float* tsrc = ts_ws + (size_t)(c * 64 + b) * 1024;
    {
        int row = t >> 3, q = t & 7;
        float4 v = *(const float4*)(tsrc + row * 32 + q * 4);
        float x[4] = {v.x, v.y, v.z, v.w};
        ushort_t hh[4], ll[4];
        #pragma unroll
        for (int j = 0; j < 4; j++) {
            hh[j] = bf16_rne(x[j]);
            ll[j] = bf16_rne(x[j] - bf16_f(hh[j]));
        }
        *(uint2*)&tsh[row][q * 4] = make_uint2(pack2(hh[0], hh[1]), pack2(hh[2], hh[3]));
        *(uint2*)&tsl[row][q * 4] = make_uint2(pack2(ll[0], ll[1]), pack2(ll[2], ll[3]));
    }
    __syncthreads();
    int w = t >> 6, lane = t & 63, quad = lane >> 4, mn = lane & 15;
    const ushort_t* M1H = Mb + 65536;
    short8 ah[2], al[2];
    #pragma unroll
    for (int mt = 0; mt < 2; mt++) {
        ah[mt] = *(short8*)&tsh[mt * 16 + mn][quad * 8];
        al[mt] = *(short8*)&tsl[mt * 16 + mn][quad * 8];
    }
    float psum = 0.f;
    #pragma unroll
    for (int nt = 0; nt < 8; nt++) {
        int h = w * 128 + nt * 16 + mn;
        short8 bh = *(const short8*)(M1H + h * 32 + quad * 8);
        short8 bl = *(const short8*)(M1H + 16384 + h * 32 + quad * 8);
        float b1v = b1[h], w2v = W2[h];
        #pragma unroll
        for (int mt = 0; mt < 2; mt++) {
            float4v acc = (float4v){0.f, 0.f, 0.f, 0.f};
            acc = __builtin_amdgcn_mfma_f32_16x16x32_bf16(ah[mt], bh, acc, 0, 0, 0);
            acc = __builtin_amdgcn_mfma_f32_16x16x32_bf16(ah[mt], bl, acc, 0, 0, 0);
            acc = __builtin_amdgcn_mfma_f32_16x16x32_bf16(al[mt], bh, acc, 0, 0, 0);
            #pragma unroll
            for (int r = 0; r < 4; r++) {
                float x = fminf(fmaxf(acc[r] + b1v, -15.f), 15.f);
                float e2 = __expf(2.f * x);
                psum += (1.f - 2.f / (e2 + 1.f)) * w2v;
            }
        }
    }
    #pragma unroll
    for (int off = 32; off >= 1; off >>= 1) psum += __shfl_down(psum, off);
    if (lane == 0) red[w] = psum;
    __syncthreads();
    if (t == 0) out_sim[b * 64 + c] = b2[0] + (red[0] + red[1] + red[2] + red[3]) * (1.f / 32.f);
}

// ---------------- k4: w[b][c] = softmax over c ----------------
__global__ __launch_bounds__(64) void k4(const float* __restrict__ sim, float* __restrict__ w_ws) {
    int b = blockIdx.x, t = threadIdx.x;
    float v = sim[b * 64 + t];
    float mx = v;
    #pragma unroll
    for (int off = 32; off >= 1; off >>= 1) mx = fmaxf(mx, __shfl_xor(mx, off));
    float p = __expf(v - mx);
    float sum = p;
    #pragma unroll
    for (int off = 32; off >= 1; off >>= 1) sum += __shfl_xor(sum, off);
    w_ws[b * 64 + t] = p / sum;
}

// ---------------- k5 (MFMA): mu_word / sigma_word; block per (b,l), 256 threads ----------------
__global__ __launch_bounds__(256) void k5(const float* __restrict__ ts_ws,
                                          const float* __restrict__ ws,
                                          const float* __restrict__ b_mu,
                                          const float* __restrict__ b_lv,
                                          float* __restrict__ out) {
    int b = blockIdx.x >> 5, l = blockIdx.x & 31;
    int t = threadIdx.x;
    __shared__ ushort_t tsh[64][32], tsl[64][32];
    __shared__ float wls[64];
    {
        int cc = t >> 2, q = t & 3;
        const float* src = ts_ws + (((size_t)cc * 64 + b) * 32 + l) * 32 + q * 8;
        #pragma unroll
        for (int half = 0; half < 2; half++) {
            float4 v = *(const float4*)(src + half * 4);
            float x[4] = {v.x, v.y, v.z, v.w};
            ushort_t hh[4], ll[4];
            #pragma unroll
            for (int j = 0; j < 4; j++) {
                hh[j] = bf16_rne(x[j]);
                ll[j] = bf16_rne(x[j] - bf16_f(hh[j]));
            }
            *(uint2*)&tsh[cc][q * 8 + half * 4] = make_uint2(pack2(hh[0], hh[1]), pack2(hh[2], hh[3]));
            *(uint2*)&tsl[cc][q * 8 + half * 4] = make_uint2(pack2(ll[0], ll[1]), pack2(ll[2], ll[3]));
        }
    }
    if (t < 64) wls[t] = ws[OFF_W + b * 64 + t];
    __syncthreads();

    int w = t >> 6, lane = t & 63, quad = lane >> 4, mn = lane & 15;
    const ushort_t* Mb = (const ushort_t*)ws;
    const ushort_t* MmuH = Mb;
    const ushort_t* MlvH = Mb + 32768;
    short8 ah[4], al[4];
    #pragma unroll
    for (int mt = 0; mt < 4; mt++) {
        ah[mt] = *(short8*)&tsh[mt * 16 + mn][quad * 8];
        al[mt] = *(short8*)&tsl[mt * 16 + mn][quad * 8];
    }
    float pm[8], pq[8], pe[8];
    #pragma unroll
    for (int nt = 0; nt < 8; nt++) {
        int h = w * 128 + nt * 16 + mn;
        {
            short8 bh = *(const short8*)(MmuH + h * 32 + quad * 8);
            short8 bl = *(const short8*)(MmuH + 16384 + h * 32 + quad * 8);
            float bmv = b_mu[h];
            float am = 0.f, aq = 0.f;
            #pragma unroll
            for (int mt = 0; mt < 4; mt++) {
                float4v acc = (float4v){0.f, 0.f, 0.f, 0.f};
                acc = __builtin_amdgcn_mfma_f32_16x16x32_bf16(ah[mt], bh, acc, 0, 0, 0);
                acc = __builtin_amdgcn_mfma_f32_16x16x32_bf16(ah[mt], bl, acc, 0, 0, 0);
                acc = __builtin_amdgcn_mfma_f32_16x16x32_bf16(al[mt], bh, acc, 0, 0, 0);
                #pragma unroll
                for (int r = 0; r < 4; r++) {
                    int cc = mt * 16 + quad * 4 + r;
                    float mu = acc[r] + bmv;
                    float wv = wls[cc];
                    am += wv * mu;
                    aq += wv * mu * mu;
                }
            }
            am += __shfl_xor(am, 16); am += __shfl_xor(am, 32);
            aq += __shfl_xor(aq, 16); aq += __shfl_xor(aq, 32);
            pm[nt] = am; pq[nt] = aq;
        }
        {
            short8 bh = *(const short8*)(MlvH + h * 32 + quad * 8);
            short8 bl = *(const short8*)(MlvH + 16384 + h * 32 + quad * 8);
            float blv = b_lv[h];
            float ae = 0.f;
            #pragma unroll
            for (int mt = 0; mt < 4; mt++) {
                float4v acc = (float4v){0.f, 0.f, 0.f, 0.f};
                acc = __builtin_amdgcn_mfma_f32_16x16x32_bf16(ah[mt], bh, acc, 0, 0, 0);
                acc = __builtin_amdgcn_mfma_f32_16x16x32_bf16(ah[mt], bl, acc, 0, 0, 0);
                acc = __builtin_amdgcn_mfma_f32_16x16x32_bf16(al[mt], bh, acc, 0, 0, 0);
                #pragma unroll
                for (int r = 0; r < 4; r++) {
                    int cc = mt * 16 + quad * 4 + r;
                    ae += wls[cc] * __expf(acc[r] + blv);
                }
            }
            ae += __shfl_xor(ae, 16); ae += __shfl_xor(ae, 32);
            pe[nt] = ae;
        }
    }
    if (quad == 0) {
        #pragma unroll
        for (int nt = 0; nt < 8; nt++) {
            int h = w * 128 + nt * 16 + mn;
            size_t idx = (size_t)(b * 32 + l) * 512 + h;
            float m = pm[nt];
            out[4096 + idx] = m;
            float var = pe[nt] + pq[nt] - m * m;
            out[4096 + 64 * 32 * 512 + idx] = sqrtf(fmaxf(var, 1e-8f));
        }
    }
}

extern "C" void kernel_launch(void* const* d_in, const int* in_sizes, int n_in,
                              void* d_out, int out_size, void* d_ws, size_t ws_size,
                              hipStream_t stream) {
    const float* images   = (const float*)d_in[0];
    const float* captions = (const float*)d_in[1];
    const int*   depends  = (const int*)d_in[2];
    const float* Wgc = (const float*)d_in[3];
    const float* Wmu = (const float*)d_in[4];
    const float* bmu = (const float*)d_in[5];
    const float* Wlv = (const float*)d_in[6];
    const float* blv = (const float*)d_in[7];
    const float* W1  = (const float*)d_in[8];
    const float* b1  = (const float*)d_in[9];
    const float* W2  = (const float*)d_in[10];
    const float* b2  = (const float*)d_in[11];
    float* out = (float*)d_out;
    float* ws  = (float*)d_ws;

    hipLaunchKernelGGL(kpre, dim3(192), dim3(256), 0, stream, Wmu, Wlv, W1, Wgc, ws);
    hipLaunchKernelGGL(k1, dim3(64), dim3(256), 0, stream, captions, depends, ws);

    const size_t CVT_FLOATS = ((size_t)2 * N_IMG_EL + 2 * N_CAP_EL) / 2;
    size_t need_floats = (size_t)OFF_CVT + CVT_FLOATS;
    bool use_mfma = ws_size >= need_floats * 4;

    if (use_mfma) {
        ushort_t* cvt = (ushort_t*)(ws + OFF_CVT);
        hipLaunchKernelGGL(kcvt, dim3((N_IMG_EL + N_CAP_EL) / 4 / 256), dim3(256), 0, stream,
                           images, captions, cvt);
        hipLaunchKernelGGL(k2a_mfma, dim3(18, 32), dim3(256), 0, stream, cvt, ws + OFF_ATTN);
        // CVT region dead after k2a_mfma; reuse for imgT hi/lo (16.8MB <= 17.8MB)
        hipLaunchKernelGGL(kcvt2, dim3(512), dim3(256), 0, stream, images, cvt);
        hipLaunchKernelGGL(k2bm, dim3(4096), dim3(64), 0, stream,
                           cvt, captions, ws + OFF_ATTN, ws, ws + OFF_TS);
    } else {
        int NW = 2048;
        while (NW > 64 && ((size_t)OFF_ATTN + (size_t)2304 * NW) * 4 > ws_size) NW >>= 1;
        for (int n0 = 0; n0 < 2048; n0 += NW) {
            hipLaunchKernelGGL(k2a, dim3(18, NW / 64), dim3(256), 0, stream,
                               images, captions, ws + OFF_ATTN, n0, NW);
            hipLaunchKernelGGL(k2b, dim3(64, NW / 64), dim3(256), 0, stream,
                               images, captions, ws + OFF_ATTN, ws, ws + OFF_TS, n0 / 32, NW);
        }
    }

    hipLaunchKernelGGL(k3, dim3(4096), dim3(256), 0, stream,
                       ws + OFF_TS, (const ushort_t*)ws, b1, W2, b2, out);
    hipLaunchKernelGGL(k4, dim3(64), dim3(64), 0, stream, out, ws + OFF_W);
    hipLaunchKernelGGL(k5, dim3(2048), dim3(256), 0, stream, ws + OFF_TS, ws, bmu, blv, out);
}

// Round 13
// 414.036 us; speedup vs baseline: 1.1876x; 1.1876x over previous
//
#include <hip/hip_runtime.h>
#include <math.h>

#define LAM 9.0f
#define EPSF 1e-8f

typedef unsigned int uint;
typedef unsigned short ushort_t;
typedef __attribute__((ext_vector_type(8))) short short8;
typedef __attribute__((ext_vector_type(4))) float float4v;

// ws layout (floats)
#define OFF_MMU 0                       // ushort planes: [hi 16384][lo 16384] per matrix
#define OFF_MLV (512*32)
#define OFF_M1  (2*512*32)
#define OFF_S   (3*512*32)              // 49152 : s[c][l] (64*32)
#define OFF_W   (OFF_S + 64*32)         // 51200 : w[b][c] (64*64)
#define OFF_QN  (OFF_W + 64*64)         // 55296 : qn[c][l][f] (64*32*32)
#define OFF_TS  (OFF_QN + 64*32*32)     // 120832: tnode_s[c][b][l][f] (64*64*32*32)
#define OFF_ATTN (OFF_TS + 64*64*32*32) // attn [2304][NW]
#define OFF_CVT  (OFF_ATTN + 2304*2048) // hi/lo bf16 arrays (ushort); REUSED by imgT2 after k2a

#define N_IMG_EL 2359296                // 2304*1024
#define N_CAP_EL 2097152                // 2048*1024
#define IMGT_EL  4194304                // imgT2 per plane (ushorts): 64b*64mt*2ks*64lane*8

__device__ __forceinline__ ushort_t bf16_rne(float x) {
    uint u = __float_as_uint(x);
    uint r = (u + 0x7fffu + ((u >> 16) & 1u)) >> 16;
    return (ushort_t)r;
}
__device__ __forceinline__ float bf16_f(ushort_t h) {
    return __uint_as_float(((uint)h) << 16);
}
__device__ __forceinline__ uint pack2(ushort_t a, ushort_t b) {
    return (uint)a | ((uint)b << 16);
}

// ---------------- kcvt: split images+captions into hi/lo bf16 (Markidis) ----------------
__global__ __launch_bounds__(256) void kcvt(const float* __restrict__ img,
                                            const float* __restrict__ cap,
                                            ushort_t* __restrict__ dst) {
    size_t i = (size_t)blockIdx.x * 256 + threadIdx.x;   // float4 index
    const float* src;
    ushort_t *H, *L;
    size_t base;
    if (i < (N_IMG_EL / 4)) {
        src = img; H = dst; L = dst + N_IMG_EL; base = i * 4;
    } else {
        src = cap; H = dst + 2 * (size_t)N_IMG_EL; L = H + N_CAP_EL; base = (i - N_IMG_EL / 4) * 4;
    }
    float4 v = *(const float4*)(src + base);
    float x[4] = {v.x, v.y, v.z, v.w};
    ushort_t hh[4], ll[4];
    #pragma unroll
    for (int j = 0; j < 4; j++) {
        hh[j] = bf16_rne(x[j]);
        ll[j] = bf16_rne(x[j] - bf16_f(hh[j]));
    }
    *(uint2*)(H + base) = make_uint2(pack2(hh[0], hh[1]), pack2(hh[2], hh[3]));
    *(uint2*)(L + base) = make_uint2(pack2(ll[0], ll[1]), pack2(ll[2], ll[3]));
}

// ---------------- kcvt2: build imgT2 in MFMA A-fragment order, hi/lo ----------------
// layout: plane*IMGT_EL + (((b*64 + mt)*2 + ks)*64 + lane)*8 ; element j of lane (quad,mn)
// = img[b][r = ks*32 + quad*8 + j][e = mt*16 + mn]  (0 for r>=36)
__global__ __launch_bounds__(256) void kcvt2(const float* __restrict__ img,
                                             ushort_t* __restrict__ dstH) {
    int b = blockIdx.x >> 3, ecg = blockIdx.x & 7;      // e-group: e = ecg*128 .. +127
    __shared__ float S[36][132];
    int t = threadIdx.x;
    for (int i = t; i < 1152; i += 256) {               // img[b][r][e-slice]
        int r = i >> 5, q = i & 31;
        *(float4*)&S[r][q * 4] = *(const float4*)(img + ((size_t)b * 36 + r) * 1024 + ecg * 128 + q * 4);
    }
    __syncthreads();
    #pragma unroll
    for (int it = 0; it < 4; it++) {
        int tup = t + it * 256;                         // (mtl, ks, lane)
        int mtl = tup >> 7, ks = (tup >> 6) & 1, lane = tup & 63;
        int quad = lane >> 4, mn = lane & 15;
        ushort_t hh[8], ll[8];
        #pragma unroll
        for (int j = 0; j < 8; j++) {
            int r = ks * 32 + quad * 8 + j;
            float v = (r < 36) ? S[r][mtl * 16 + mn] : 0.f;
            hh[j] = bf16_rne(v);
            ll[j] = bf16_rne(v - bf16_f(hh[j]));
        }
        int mt = ecg * 8 + mtl;
        size_t off = ((((size_t)b * 64 + mt) * 2 + ks) * 64 + lane) * 8;
        uint4 uh, ul;
        uh.x = pack2(hh[0], hh[1]); uh.y = pack2(hh[2], hh[3]);
        uh.z = pack2(hh[4], hh[5]); uh.w = pack2(hh[6], hh[7]);
        ul.x = pack2(ll[0], ll[1]); ul.y = pack2(ll[2], ll[3]);
        ul.z = pack2(ll[4], ll[5]); ul.w = pack2(ll[6], ll[7]);
        *(uint4*)(dstH + off) = uh;
        *(uint4*)(dstH + IMGT_EL + off) = ul;
    }
}

// ---------------- k2a_mfma: attn = IMG(2304x1024) @ CAP^T via split-bf16 MFMA ----------------
__global__ __launch_bounds__(256) void k2a_mfma(const ushort_t* __restrict__ cvt,
                                                float* __restrict__ C) {
    const ushort_t* imgH = cvt;
    const ushort_t* imgL = cvt + N_IMG_EL;
    const ushort_t* capH = cvt + 2 * (size_t)N_IMG_EL;
    const ushort_t* capL = capH + N_CAP_EL;
    __shared__ ushort_t Ah[128][32], Al[128][32], Bh[64][32], Bl[64][32];
    int t = threadIdx.x, w = t >> 6, lane = t & 63;
    int quad = lane >> 4, mn = lane & 15;
    int m0 = blockIdx.x * 128, n0 = blockIdx.y * 64;
    float4v acc[2][4];
    #pragma unroll
    for (int i = 0; i < 2; i++)
        #pragma unroll
        for (int j = 0; j < 4; j++) acc[i][j] = (float4v){0.f, 0.f, 0.f, 0.f};

    for (int kc = 0; kc < 32; kc++) {
        #pragma unroll
        for (int j = 0; j < 6; j++) {
            int ch = t + j * 256;                   // 1536 16B chunks
            if (ch < 512) {
                int row = ch >> 2, seg = ch & 3;
                *(uint4*)&Ah[row][seg * 8] = *(const uint4*)(imgH + (size_t)(m0 + row) * 1024 + kc * 32 + seg * 8);
            } else if (ch < 1024) {
                int r2 = ch - 512, row = r2 >> 2, seg = r2 & 3;
                *(uint4*)&Al[row][seg * 8] = *(const uint4*)(imgL + (size_t)(m0 + row) * 1024 + kc * 32 + seg * 8);
            } else if (ch < 1280) {
                int r2 = ch - 1024, row = r2 >> 2, seg = r2 & 3;
                *(uint4*)&Bh[row][seg * 8] = *(const uint4*)(capH + (size_t)(n0 + row) * 1024 + kc * 32 + seg * 8);
            } else {
                int r2 = ch - 1280, row = r2 >> 2, seg = r2 & 3;
                *(uint4*)&Bl[row][seg * 8] = *(const uint4*)(capL + (size_t)(n0 + row) * 1024 + kc * 32 + seg * 8);
            }
        }
        __syncthreads();
        short8 ah[2], al[2];
        #pragma unroll
        for (int tm = 0; tm < 2; tm++) {
            ah[tm] = *(short8*)&Ah[w * 32 + tm * 16 + mn][quad * 8];
            al[tm] = *(short8*)&Al[w * 32 + tm * 16 + mn][quad * 8];
        }
        #pragma unroll
        for (int nt = 0; nt < 4; nt++) {
            short8 bh = *(short8*)&Bh[nt * 16 + mn][quad * 8];
            short8 bl = *(short8*)&Bl[nt * 16 + mn][quad * 8];
            #pragma unroll
            for (int tm = 0; tm < 2; tm++) {
                acc[tm][nt] = __builtin_amdgcn_mfma_f32_16x16x32_bf16(ah[tm], bh, acc[tm][nt], 0, 0, 0);
                acc[tm][nt] = __builtin_amdgcn_mfma_f32_16x16x32_bf16(ah[tm], bl, acc[tm][nt], 0, 0, 0);
                acc[tm][nt] = __builtin_amdgcn_mfma_f32_16x16x32_bf16(al[tm], bh, acc[tm][nt], 0, 0, 0);
            }
        }
        __syncthreads();
    }
    #pragma unroll
    for (int tm = 0; tm < 2; tm++)
        #pragma unroll
        for (int nt = 0; nt < 4; nt++)
            #pragma unroll
            for (int r = 0; r < 4; r++) {
                int mrow = m0 + w * 32 + tm * 16 + quad * 4 + r;
                int ncol = n0 + nt * 16 + mn;
                C[(size_t)mrow * 2048 + ncol] = acc[tm][nt][r];
            }
}

// ---------------- kpre: M_X = W_X @ W_gc (512x32); emit bf16 hi/lo planes ----------------
__global__ __launch_bounds__(256) void kpre(const float* __restrict__ Wmu,
                                            const float* __restrict__ Wlv,
                                            const float* __restrict__ W1,
                                            const float* __restrict__ Wgc,
                                            float* __restrict__ ws) {
    int m = blockIdx.x >> 6;            // 0..2
    int hg = blockIdx.x & 63;           // 0..63
    int h0 = hg * 8;
    const float* W = (m == 0) ? Wmu : (m == 1) ? Wlv : W1;
    __shared__ float Gs[64][32];
    __shared__ float Ws[8][68];
    int t = threadIdx.x;
    int h = t >> 5, f = t & 31;
    float acc = 0.f;
    for (int kc = 0; kc < 8; kc++) {
        for (int i = t; i < 512; i += 256) {
            int row = i >> 3, c4 = i & 7;
            *(float4*)&Gs[row][c4 * 4] = *(const float4*)(Wgc + (kc * 64 + row) * 32 + c4 * 4);
        }
        if (t < 128) {
            int hh = t >> 4, c4 = t & 15;
            *(float4*)&Ws[hh][c4 * 4] = *(const float4*)(W + (size_t)(h0 + hh) * 512 + kc * 64 + c4 * 4);
        }
        __syncthreads();
        #pragma unroll 4
        for (int k = 0; k < 64; k++) acc += Ws[h][k] * Gs[k][f];
        __syncthreads();
    }
    ushort_t* Mb = (ushort_t*)ws + m * 32768;       // [hi 16384][lo 16384]
    ushort_t hi = bf16_rne(acc);
    ushort_t lo = bf16_rne(acc - bf16_f(hi));
    Mb[(h0 + h) * 32 + f] = hi;
    Mb[16384 + (h0 + h) * 32 + f] = lo;
}

// ---------------- k1: per caption: words_sim -> adj -> s[c][l] ; + qn[c][l][f] ----------------
__global__ __launch_bounds__(256) void k1(const float* __restrict__ captions,
                                          const int* __restrict__ depends,
                                          float* __restrict__ ws) {
    int c = blockIdx.x;
    __shared__ float caps[32][65];
    __shared__ float G[32][33];
    __shared__ float adj[32][33];
    int t = threadIdx.x;
    int l2 = t & 31, l1_0 = t >> 5;
    float acc[4] = {0.f, 0.f, 0.f, 0.f};
    const float* cap = captions + (size_t)c * 32 * 1024;

    for (int kc = 0; kc < 16; kc++) {
        for (int i = t; i < 512; i += 256) {
            int ll = i >> 4, q = i & 15;
            float4 v = *(const float4*)(cap + ll * 1024 + kc * 64 + q * 4);
            caps[ll][q * 4 + 0] = v.x; caps[ll][q * 4 + 1] = v.y;
            caps[ll][q * 4 + 2] = v.z; caps[ll][q * 4 + 3] = v.w;
        }
        __syncthreads();
        #pragma unroll 4
        for (int k = 0; k < 64; k++) {
            float cv = caps[l2][k];
            #pragma unroll
            for (int i = 0; i < 4; i++) acc[i] += caps[l1_0 + 8 * i][k] * cv;
        }
        __syncthreads();
    }
    #pragma unroll
    for (int i = 0; i < 4; i++) G[l1_0 + 8 * i][l2] = acc[i];
    for (int i = t; i < 32 * 33; i += 256) ((float*)adj)[i] = 0.f;
    __syncthreads();

    if (t < 32) {
        float mx = -1e30f;
        for (int n = 0; n < 32; n++) mx = fmaxf(mx, LAM * G[t][n]);
        float sum = 0.f;
        for (int n = 0; n < 32; n++) { float p = __expf(LAM * G[t][n] - mx); G[t][n] = p; sum += p; }
        float inv = 1.f / sum;
        for (int n = 0; n < 32; n++) G[t][n] *= inv;
    }
    __syncthreads();
    if (t >= 1 && t < 30) {
        int d0 = depends[c * 60 + t * 2 + 0];
        int d1 = depends[c * 60 + t * 2 + 1];
        adj[d0][d1] = 1.f;
        adj[d1][d0] = 1.f;
    }
    __syncthreads();
    if (t < 32) adj[t][t] += 1.f;
    __syncthreads();
    if (t < 32) {
        float ss = 0.f, sw = 0.f;
        for (int n = 0; n < 32; n++) { float mm = adj[t][n] * G[t][n]; ss += mm * mm; }
        float inv = 1.f / (sqrtf(ss) + EPSF);
        for (int n = 0; n < 32; n++) sw += adj[t][n] * G[t][n] * adj[t][n];
        ws[OFF_S + c * 32 + t] = sw * inv;
    }
    for (int p = t; p < 1024; p += 256) {
        int l = p >> 5, f = p & 31;
        const float* cp = cap + (size_t)l * 1024 + f * 32;
        float q2 = 0.f;
        #pragma unroll
        for (int q = 0; q < 8; q++) {
            float4 v = *(const float4*)(cp + q * 4);
            q2 += v.x * v.x + v.y * v.y + v.z * v.z + v.w * v.w;
        }
        ws[OFF_QN + c * 1024 + p] = sqrtf(q2);
    }
}

// ---------------- k2a (fp32 fallback) ----------------
__global__ __launch_bounds__(256) void k2a(const float* __restrict__ A,
                                           const float* __restrict__ Bm,
                                           float* __restrict__ C,
                                           int n0, int NW) {
    __shared__ float As[16][132];
    __shared__ float Bs[16][68];
    int m0 = blockIdx.x * 128;
    int nb0 = n0 + blockIdx.y * 64;
    int t = threadIdx.x;
    int tm = t >> 4, tn = t & 15;
    float acc[8][4] = {};
    for (int kc = 0; kc < 64; kc++) {
        #pragma unroll
        for (int j = 0; j < 2; j++) {
            int idx = t + j * 256;
            int row = idx >> 2, kq = idx & 3;
            float4 v = *(const float4*)(A + (size_t)(m0 + row) * 1024 + kc * 16 + kq * 4);
            As[kq * 4 + 0][row] = v.x; As[kq * 4 + 1][row] = v.y;
            As[kq * 4 + 2][row] = v.z; As[kq * 4 + 3][row] = v.w;
        }
        {
            int row = t >> 2, kq = t & 3;
            float4 v = *(const float4*)(Bm + (size_t)(nb0 + row) * 1024 + kc * 16 + kq * 4);
            Bs[kq * 4 + 0][row] = v.x; Bs[kq * 4 + 1][row] = v.y;
            Bs[kq * 4 + 2][row] = v.z; Bs[kq * 4 + 3][row] = v.w;
        }
        __syncthreads();
        #pragma unroll
        for (int kk = 0; kk < 16; kk++) {
            float a0[4], a1[4], bb[4];
            *(float4*)a0 = *(float4*)&As[kk][tm * 8];
            *(float4*)a1 = *(float4*)&As[kk][tm * 8 + 4];
            *(float4*)bb = *(float4*)&Bs[kk][tn * 4];
            #pragma unroll
            for (int i = 0; i < 4; i++)
                #pragma unroll
                for (int j2 = 0; j2 < 4; j2++) {
                    acc[i][j2]     += a0[i] * bb[j2];
                    acc[i + 4][j2] += a1[i] * bb[j2];
                }
        }
        __syncthreads();
    }
    int cw0 = nb0 - n0 + tn * 4;
    #pragma unroll
    for (int i = 0; i < 8; i++) {
        float4 v = make_float4(acc[i][0], acc[i][1], acc[i][2], acc[i][3]);
        *(float4*)(C + (size_t)(m0 + tm * 8 + i) * NW + cw0) = v;
    }
}

// ---------------- k2bm v5.1: per (c-pair, b) one wave; frag-order imgT2, 2 captions/wave ------
__global__ __launch_bounds__(64) void k2bm(const ushort_t* __restrict__ imgT,
                                           const float* __restrict__ captions,
                                           const float* __restrict__ attn,
                                           const float* __restrict__ ws,
                                           float* __restrict__ ts_out) {
    int cpair = blockIdx.x >> 6, b = blockIdx.x & 63;
    int c0 = cpair * 2;
    __shared__ union {
        float A[2][36][36];                     // attn tiles (phase 1)
        struct {
            float T[2][32][36];                 // tnode tiles (phase 2)
            float capf[2][32][36];              // cap f-slices (phase 2)
        } p2;
    } u;
    int t = threadIdx.x;
    int quad = t >> 4, mn = t & 15;

    // phase 0: load 2 attn tiles
    for (int i = t; i < 576; i += 64) {
        int ci = i >= 288;
        int i2 = i - ci * 288;
        int r = i2 >> 3, q = i2 & 7;
        *(float4*)&u.A[ci][r][q * 4] =
            *(const float4*)(attn + (size_t)(b * 36 + r) * 2048 + (c0 + ci) * 32 + q * 4);
    }
    __syncthreads();
    for (int i = t; i < 72; i += 64) {          // leaky + l2norm over words, per (ci, region)
        int ci = i >= 36, r = i - 36 * ci;      // FIX: strided loop (block has only 64 threads)
        float ss = 0.f;
        #pragma unroll
        for (int l = 0; l < 32; l++) {
            float v = u.A[ci][r][l];
            v = (v >= 0.f) ? v : 0.1f * v;
            u.A[ci][r][l] = v; ss += v * v;
        }
        float inv = 1.f / (sqrtf(ss) + EPSF);
        #pragma unroll
        for (int l = 0; l < 32; l++) u.A[ci][r][l] *= inv;
    }
    __syncthreads();
    if (t < 64) {                               // softmax over regions per (ci, word)
        int ci = t >> 5, l = t & 31;
        float mx = -1e30f;
        for (int r = 0; r < 36; r++) mx = fmaxf(mx, u.A[ci][r][l]);
        mx *= LAM;
        float sum = 0.f;
        for (int r = 0; r < 36; r++) { float p = __expf(LAM * u.A[ci][r][l] - mx); u.A[ci][r][l] = p; sum += p; }
        float inv = 1.f / sum;
        for (int r = 0; r < 36; r++) u.A[ci][r][l] *= inv;
    }
    __syncthreads();

    // B-frags (k=r, n=l) for both captions, split hi/lo in-register
    short8 bh[2][2][2], bl[2][2][2];            // [ci][nt][ks]
    #pragma unroll
    for (int ci = 0; ci < 2; ci++)
        #pragma unroll
        for (int nt = 0; nt < 2; nt++)
            #pragma unroll
            for (int ks = 0; ks < 2; ks++) {
                union { short8 v; ushort_t u8[8]; } H, L;
                #pragma unroll
                for (int j = 0; j < 8; j++) {
                    int r = ks * 32 + quad * 8 + j;
                    float v = (r < 36) ? u.A[ci][r][nt * 16 + mn] : 0.f;
                    ushort_t hi = bf16_rne(v);
                    H.u8[j] = hi;
                    L.u8[j] = bf16_rne(v - bf16_f(hi));
                }
                bh[ci][nt][ks] = H.v;
                bl[ci][nt][ks] = L.v;
            }
    __syncthreads();                            // A dead; union space becomes T/capf

    const ushort_t* ibH = imgT + (size_t)b * 65536;    // frag-order: ((mt*2+ks)*64 + lane)*8
    const ushort_t* ibL = ibH + IMGT_EL;
    const float* qnp = ws + OFF_QN;
    float sv[2][2];                             // [ci][nt]
    #pragma unroll
    for (int ci = 0; ci < 2; ci++)
        #pragma unroll
        for (int nt = 0; nt < 2; nt++)
            sv[ci][nt] = ws[OFF_S + (c0 + ci) * 32 + nt * 16 + mn];

    for (int f = 0; f < 32; f++) {
        __syncthreads();                        // protect capf from previous-f readers
        #pragma unroll
        for (int j = 0; j < 8; j++) {           // stage cap f-slices, coalesced
            int id = t + j * 64;
            int ci = id >> 8, id2 = id & 255;
            int l = id2 >> 3, q = id2 & 7;
            *(float4*)&u.p2.capf[ci][l][q * 4] =
                *(const float4*)(captions + (size_t)(c0 + ci) * 32768 + (size_t)l * 1024 + f * 32 + q * 4);
        }
        __syncthreads();
        float num[2][2] = {}, w2a[2][2] = {};
        #pragma unroll
        for (int h = 0; h < 2; h++) {
            int mt = f * 2 + h;
            short8 ah0 = *(const short8*)(ibH + ((size_t)(mt * 2 + 0) * 64 + t) * 8);
            short8 ah1 = *(const short8*)(ibH + ((size_t)(mt * 2 + 1) * 64 + t) * 8);
            short8 al0 = *(const short8*)(ibL + ((size_t)(mt * 2 + 0) * 64 + t) * 8);
            short8 al1 = *(const short8*)(ibL + ((size_t)(mt * 2 + 1) * 64 + t) * 8);
            #pragma unroll
            for (int ci = 0; ci < 2; ci++)
                #pragma unroll
                for (int nt = 0; nt < 2; nt++) {
                    float4v acc = (float4v){0.f, 0.f, 0.f, 0.f};
                    acc = __builtin_amdgcn_mfma_f32_16x16x32_bf16(ah0, bh[ci][nt][0], acc, 0, 0, 0);
                    acc = __builtin_amdgcn_mfma_f32_16x16x32_bf16(ah0, bl[ci][nt][0], acc, 0, 0, 0);
                    acc = __builtin_amdgcn_mfma_f32_16x16x32_bf16(al0, bh[ci][nt][0], acc, 0, 0, 0);
                    acc = __builtin_amdgcn_mfma_f32_16x16x32_bf16(ah1, bh[ci][nt][1], acc, 0, 0, 0);
                    acc = __builtin_amdgcn_mfma_f32_16x16x32_bf16(ah1, bl[ci][nt][1], acc, 0, 0, 0);
                    acc = __builtin_amdgcn_mfma_f32_16x16x32_bf16(al1, bh[ci][nt][1], acc, 0, 0, 0);
                    // lane holds wctxT[e = mt*16 + quad*4 + r][l = nt*16 + mn]
                    float4 cv = *(float4*)&u.p2.capf[ci][nt * 16 + mn][h * 16 + quad * 4];
                    num[ci][nt] += cv.x * acc[0] + cv.y * acc[1] + cv.z * acc[2] + cv.w * acc[3];
                    w2a[ci][nt] += acc[0] * acc[0] + acc[1] * acc[1] + acc[2] * acc[2] + acc[3] * acc[3];
                }
        }
        #pragma unroll
        for (int ci = 0; ci < 2; ci++)
            #pragma unroll
            for (int nt = 0; nt < 2; nt++) {
                float n = num[ci][nt], w = w2a[ci][nt];
                n += __shfl_xor(n, 16); n += __shfl_xor(n, 32);
                w += __shfl_xor(w, 16); w += __shfl_xor(w, 32);
                if (quad == 0) {
                    int l = nt * 16 + mn;
                    float den = fmaxf(qnp[(c0 + ci) * 1024 + l * 32 + f] * sqrtf(w), EPSF);
                    u.p2.T[ci][l][f] = (n / den) * sv[ci][nt];
                }
            }
    }
    __syncthreads();
    // coalesced burst: both tnode tiles contiguous in ts_out
    #pragma unroll
    for (int j = 0; j < 8; j++) {
        int id = t + j * 64;
        int ci = id >> 8, id2 = id & 255;
        int l = id2 >> 3, q = id2 & 7;
        *(float4*)(ts_out + ((size_t)(c0 + ci) * 64 + b) * 1024 + l * 32 + q * 4) =
            *(float4*)&u.p2.T[ci][l][q * 4];
    }
}

// ---------------- k2b (fp32 fallback, validated R4 version) ----------------
__global__ __launch_bounds__(256) void k2b(const float* __restrict__ images,
                                           const float* __restrict__ captions,
                                           const float* __restrict__ attn,
                                           const float* __restrict__ ws,
                                           float* __restrict__ ts_out,
                                           int c0, int NW) {
    int b = blockIdx.x;
    int cw = blockIdx.y;
    int ca = c0 + cw * 2;
    __shared__ float A2[2][36][36];
    __shared__ float Ims[36][256];
    __shared__ float scs[2][32];
    const float* img = images + (size_t)b * 36 * 1024;
    int t = threadIdx.x;
    int el = t & 63;
    int lg = t >> 6;

    for (int i = t; i < 576; i += 256) {
        int r = i >> 4, q = i & 15;
        float4 v = *(const float4*)(attn + (size_t)(b * 36 + r) * NW + cw * 64 + q * 4);
        *(float4*)&A2[q >> 3][r][(q & 7) * 4] = v;
    }
    __syncthreads();
    if (t < 72) {
        int ci = t >= 36, r = t - 36 * ci;
        float ss = 0.f;
        #pragma unroll
        for (int l = 0; l < 32; l++) {
            float v = A2[ci][r][l];
            v = (v >= 0.f) ? v : 0.1f * v;
            A2[ci][r][l] = v; ss += v * v;
        }
        float inv = 1.f / (sqrtf(ss) + EPSF);
        #pragma unroll
        for (int l = 0; l < 32; l++) A2[ci][r][l] *= inv;
    }
    __syncthreads();
    if (t < 64) {
        int ci = t >> 5, l = t & 31;
        float mx = -1e30f;
        for (int r = 0; r < 36; r++) mx = fmaxf(mx, A2[ci][r][l]);
        mx *= LAM;
        float sum = 0.f;
        for (int r = 0; r < 36; r++) { float p = __expf(LAM * A2[ci][r][l] - mx); A2[ci][r][l] = p; sum += p; }
        float inv = 1.f / sum;
        for (int r = 0; r < 36; r++) A2[ci][r][l] *= inv;
    } else if (t >= 128 && t < 192) {
        int i = t - 128;
        scs[i >> 5][i & 31] = ws[OFF_S + (ca + (i >> 5)) * 32 + (i & 31)];
    }
    __syncthreads();

    const float* qn = ws + OFF_QN;
    for (int g = 0; g < 4; g++) {
        for (int i = t; i < 2304; i += 256) {
            int r = i >> 6, q = i & 63;
            *(float4*)&Ims[r][q * 4] = *(const float4*)(img + (size_t)r * 1024 + g * 256 + q * 4);
        }
        __syncthreads();

        float acc[2][8][4] = {};
        #pragma unroll 2
        for (int r = 0; r < 36; r++) {
            float4 iv = *(float4*)&Ims[r][el * 4];
            float ivv[4] = {iv.x, iv.y, iv.z, iv.w};
            #pragma unroll
            for (int ci = 0; ci < 2; ci++) {
                float av[8];
                *(float4*)&av[0] = *(float4*)&A2[ci][r][lg * 8];
                *(float4*)&av[4] = *(float4*)&A2[ci][r][lg * 8 + 4];
                #pragma unroll
                for (int i = 0; i < 8; i++)
                    #pragma unroll
                    for (int e = 0; e < 4; e++)
                        acc[ci][i][e] += av[i] * ivv[e];
            }
        }

        int fb = el >> 3;
        int f = g * 8 + fb;
        #pragma unroll
        for (int ci = 0; ci < 2; ci++) {
            int c = ca + ci;
            const float* cap = captions + (size_t)c * 32 * 1024 + g * 256;
            #pragma unroll
            for (int i = 0; i < 8; i++) {
                int l = lg * 8 + i;
                float4 cv = *(const float4*)(cap + (size_t)l * 1024 + el * 4);
                float num = cv.x * acc[ci][i][0] + cv.y * acc[ci][i][1]
                          + cv.z * acc[ci][i][2] + cv.w * acc[ci][i][3];
                float w2 = acc[ci][i][0] * acc[ci][i][0] + acc[ci][i][1] * acc[ci][i][1]
                         + acc[ci][i][2] * acc[ci][i][2] + acc[ci][i][3] * acc[ci][i][3];
                num += __shfl_down(num, 4); w2 += __shfl_down(w2, 4);
                num += __shfl_down(num, 2); w2 += __shfl_down(w2, 2);
                num += __shfl_down(num, 1); w2 += __shfl_down(w2, 1);
                if ((el & 7) == 0) {
                    float den = fmaxf(qn[c * 1024 + l * 32 + f] * sqrtf(w2), EPSF);
                    ts_out[(((size_t)c * 64 + b) * 32 + l) * 32 + f] = (num / den) * scs[ci][l];
                }
            }
        }
        __syncthreads();
    }
}

// ---------------- k3 (MFMA): similarities[b][c] = mean_l W2·tanh(ts@M1^T + b1) + b2 ----------------
__global__ __launch_bounds__(256) void k3(const float* __restrict__ ts_ws,
                                          const ushort_t* __restrict__ Mb,
                                          const float* __restrict__ b1,
                                          const float* __restrict__ W2,
                                          const float* __restrict__ b2,
                                          float* __restrict__ out_sim) {
    int c = blockIdx.x >> 6, b = blockIdx.x & 63;
    __shared__ ushort_t tsh[32][32], tsl[32][32];
    __shared__ float red[4];
    int t = threadIdx.x;
    const float* tsrc = ts_ws + (size_t)(c * 64 + b) * 1024;
    {
        int row = t >> 3, q = t & 7;
        float4 v = *(const float4*)(tsrc + row * 32 + q * 4);
        float x[4] = {v.x, v.y, v.z, v.w};
        ushort_t hh[4], ll[4];
        #pragma unroll
        for (int j = 0; j < 4; j++) {
            hh[j] = bf16_rne(x[j]);
            ll[j] = bf16_rne(x[j] - bf16_f(hh[j]));
        }
        *(uint2*)&tsh[row][q * 4] = make_uint2(pack2(hh[0], hh[1]), pack2(hh[2], hh[3]));
        *(uint2*)&tsl[row][q * 4] = make_uint2(pack2(ll[0], ll[1]), pack2(ll[2], ll[3]));
    }
    __syncthreads();
    int w = t >> 6, lane = t & 63, quad = lane >> 4, mn = lane & 15;
    const ushort_t* M1H = Mb + 65536;
    short8 ah[2], al[2];
    #pragma unroll
    for (int mt = 0; mt < 2; mt++) {
        ah[mt] = *(short8*)&tsh[mt * 16 + mn][quad * 8];
        al[mt] = *(short8*)&tsl[mt * 16 + mn][quad * 8];
    }
    float psum = 0.f;
    #pragma unroll
    for (int nt = 0; nt < 8; nt++) {
        int h = w * 128 + nt * 16 + mn;
        short8 bh = *(const short8*)(M1H + h * 32 + quad * 8);
        short8 bl = *(const short8*)(M1H + 16384 + h * 32 + quad * 8);
        float b1v = b1[h], w2v = W2[h];
        #pragma unroll
        for (int mt = 0; mt < 2; mt++) {
            float4v acc = (float4v){0.f, 0.f, 0.f, 0.f};
            acc = __builtin_amdgcn_mfma_f32_16x16x32_bf16(ah[mt], bh, acc, 0, 0, 0);
            acc = __builtin_amdgcn_mfma_f32_16x16x32_bf16(ah[mt], bl, acc, 0, 0, 0);
            acc = __builtin_amdgcn_mfma_f32_16x16x32_bf16(al[mt], bh, acc, 0, 0, 0);
            #pragma unroll
            for (int r = 0; r < 4; r++) {
                float x = fminf(fmaxf(acc[r] + b1v, -15.f), 15.f);
                float e2 = __expf(2.f * x);
                psum += (1.f - 2.f / (e2 + 1.f)) * w2v;
            }
        }
    }
    #pragma unroll
    for (int off = 32; off >= 1; off >>= 1) psum += __shfl_down(psum, off);
    if (lane == 0) red[w] = psum;
    __syncthreads();
    if (t == 0) out_sim[b * 64 + c] = b2[0] + (red[0] + red[1] + red[2] + red[3]) * (1.f / 32.f);
}

// ---------------- k4: w[b][c] = softmax over c ----------------
__global__ __launch_bounds__(64) void k4(const float* __restrict__ sim, float* __restrict__ w_ws) {
    int b = blockIdx.x, t = threadIdx.x;
    float v = sim[b * 64 + t];
    float mx = v;
    #pragma unroll
    for (int off = 32; off >= 1; off >>= 1) mx = fmaxf(mx, __shfl_xor(mx, off));
    float p = __expf(v - mx);
    float sum = p;
    #pragma unroll
    for (int off = 32; off >= 1; off >>= 1) sum += __shfl_xor(sum, off);
    w_ws[b * 64 + t] = p / sum;
}

// ---------------- k5 (MFMA): mu_word / sigma_word; block per (b,l), 256 threads ----------------
__global__ __launch_bounds__(256) void k5(const float* __restrict__ ts_ws,
                                          const float* __restrict__ ws,
                                          const float* __restrict__ b_mu,
                                          const float* __restrict__ b_lv,
                                          float* __restrict__ out) {
    int b = blockIdx.x >> 5, l = blockIdx.x & 31;
    int t = threadIdx.x;
    __shared__ ushort_t tsh[64][32], tsl[64][32];
    __shared__ float wls[64];
    {
        int cc = t >> 2, q = t & 3;
        const float* src = ts_ws + (((size_t)cc * 64 + b) * 32 + l) * 32 + q * 8;
        #pragma unroll
        for (int half = 0; half < 2; half++) {
            float4 v = *(const float4*)(src + half * 4);
            float x[4] = {v.x, v.y, v.z, v.w};
            ushort_t hh[4], ll[4];
            #pragma unroll
            for (int j = 0; j < 4; j++) {
                hh[j] = bf16_rne(x[j]);
                ll[j] = bf16_rne(x[j] - bf16_f(hh[j]));
            }
            *(uint2*)&tsh[cc][q * 8 + half * 4] = make_uint2(pack2(hh[0], hh[1]), pack2(hh[2], hh[3]));
            *(uint2*)&tsl[cc][q * 8 + half * 4] = make_uint2(pack2(ll[0], ll[1]), pack2(ll[2], ll[3]));
        }
    }
    if (t < 64) wls[t] = ws[OFF_W + b * 64 + t];
    __syncthreads();

    int w = t >> 6, lane = t & 63, quad = lane >> 4, mn = lane & 15;
    const ushort_t* Mb = (const ushort_t*)ws;
    const ushort_t* MmuH = Mb;
    const ushort_t* MlvH = Mb + 32768;
    short8 ah[4], al[4];
    #pragma unroll
    for (int mt = 0; mt < 4; mt++) {
        ah[mt] = *(short8*)&tsh[mt * 16 + mn][quad * 8];
        al[mt] = *(short8*)&tsl[mt * 16 + mn][quad * 8];
    }
    float pm[8], pq[8], pe[8];
    #pragma unroll
    for (int nt = 0; nt < 8; nt++) {
        int h = w * 128 + nt * 16 + mn;
        {
            short8 bh = *(const short8*)(MmuH + h * 32 + quad * 8);
            short8 bl = *(const short8*)(MmuH + 16384 + h * 32 + quad * 8);
            float bmv = b_mu[h];
            float am = 0.f, aq = 0.f;
            #pragma unroll
            for (int mt = 0; mt < 4; mt++) {
                float4v acc = (float4v){0.f, 0.f, 0.f, 0.f};
                acc = __builtin_amdgcn_mfma_f32_16x16x32_bf16(ah[mt], bh, acc, 0, 0, 0);
                acc = __builtin_amdgcn_mfma_f32_16x16x32_bf16(ah[mt], bl, acc, 0, 0, 0);
                acc = __builtin_amdgcn_mfma_f32_16x16x32_bf16(al[mt], bh, acc, 0, 0, 0);
                #pragma unroll
                for (int r = 0; r < 4; r++) {
                    int cc = mt * 16 + quad * 4 + r;
                    float mu = acc[r] + bmv;
                    float wv = wls[cc];
                    am += wv * mu;
                    aq += wv * mu * mu;
                }
            }
            am += __shfl_xor(am, 16); am += __shfl_xor(am, 32);
            aq += __shfl_xor(aq, 16); aq += __shfl_xor(aq, 32);
            pm[nt] = am; pq[nt] = aq;
        }
        {
            short8 bh = *(const short8*)(MlvH + h * 32 + quad * 8);
            short8 bl = *(const short8*)(MlvH + 16384 + h * 32 + quad * 8);
            float blv = b_lv[h];
            float ae = 0.f;
            #pragma unroll
            for (int mt = 0; mt < 4; mt++) {
                float4v acc = (float4v){0.f, 0.f, 0.f, 0.f};
                acc = __builtin_amdgcn_mfma_f32_16x16x32_bf16(ah[mt], bh, acc, 0, 0, 0);
                acc = __builtin_amdgcn_mfma_f32_16x16x32_bf16(ah[mt], bl, acc, 0, 0, 0);
                acc = __builtin_amdgcn_mfma_f32_16x16x32_bf16(al[mt], bh, acc, 0, 0, 0);
                #pragma unroll
                for (int r = 0; r < 4; r++) {
                    int cc = mt * 16 + quad * 4 + r;
                    ae += wls[cc] * __expf(acc[r] + blv);
                }
            }
            ae += __shfl_xor(ae, 16); ae += __shfl_xor(ae, 32);
            pe[nt] = ae;
        }
    }
    if (quad == 0) {
        #pragma unroll
        for (int nt = 0; nt < 8; nt++) {
            int h = w * 128 + nt * 16 + mn;
            size_t idx = (size_t)(b * 32 + l) * 512 + h;
            float m = pm[nt];
            out[4096 + idx] = m;
            float var = pe[nt] + pq[nt] - m * m;
            out[4096 + 64 * 32 * 512 + idx] = sqrtf(fmaxf(var, 1e-8f));
        }
    }
}

extern "C" void kernel_launch(void* const* d_in, const int* in_sizes, int n_in,
                              void* d_out, int out_size, void* d_ws, size_t ws_size,
                              hipStream_t stream) {
    const float* images   = (const float*)d_in[0];
    const float* captions = (const float*)d_in[1];
    const int*   depends  = (const int*)d_in[2];
    const float* Wgc = (const float*)d_in[3];
    const float* Wmu = (const float*)d_in[4];
    const float* bmu = (const float*)d_in[5];
    const float* Wlv = (const float*)d_in[6];
    const float* blv = (const float*)d_in[7];
    const float* W1  = (const float*)d_in[8];
    const float* b1  = (const float*)d_in[9];
    const float* W2  = (const float*)d_in[10];
    const float* b2  = (const float*)d_in[11];
    float* out = (float*)d_out;
    float* ws  = (float*)d_ws;

    hipLaunchKernelGGL(kpre, dim3(192), dim3(256), 0, stream, Wmu, Wlv, W1, Wgc, ws);
    hipLaunchKernelGGL(k1, dim3(64), dim3(256), 0, stream, captions, depends, ws);

    const size_t CVT_FLOATS = ((size_t)2 * N_IMG_EL + 2 * N_CAP_EL) / 2;
    size_t need_floats = (size_t)OFF_CVT + CVT_FLOATS;
    bool use_mfma = ws_size >= need_floats * 4;

    if (use_mfma) {
        ushort_t* cvt = (ushort_t*)(ws + OFF_CVT);
        hipLaunchKernelGGL(kcvt, dim3((N_IMG_EL + N_CAP_EL) / 4 / 256), dim3(256), 0, stream,
                           images, captions, cvt);
        hipLaunchKernelGGL(k2a_mfma, dim3(18, 32), dim3(256), 0, stream, cvt, ws + OFF_ATTN);
        // CVT region dead after k2a_mfma; reuse for frag-order imgT2 hi/lo (16.8MB <= 17.8MB)
        hipLaunchKernelGGL(kcvt2, dim3(512), dim3(256), 0, stream, images, cvt);
        hipLaunchKernelGGL(k2bm, dim3(2048), dim3(64), 0, stream,
                           cvt, captions, ws + OFF_ATTN, ws, ws + OFF_TS);
    } else {
        int NW = 2048;
        while (NW > 64 && ((size_t)OFF_ATTN + (size_t)2304 * NW) * 4 > ws_size) NW >>= 1;
        for (int n0 = 0; n0 < 2048; n0 += NW) {
            hipLaunchKernelGGL(k2a, dim3(18, NW / 64), dim3(256), 0, stream,
                               images, captions, ws + OFF_ATTN, n0, NW);
            hipLaunchKernelGGL(k2b, dim3(64, NW / 64), dim3(256), 0, stream,
                               images, captions, ws + OFF_ATTN, ws, ws + OFF_TS, n0 / 32, NW);
        }
    }

    hipLaunchKernelGGL(k3, dim3(4096), dim3(256), 0, stream,
                       ws + OFF_TS, (const ushort_t*)ws, b1, W2, b2, out);
    hipLaunchKernelGGL(k4, dim3(64), dim3(64), 0, stream, out, ws + OFF_W);
    hipLaunchKernelGGL(k5, dim3(2048), dim3(256), 0, stream, ws + OFF_TS, ws, bmu, blv, out);
}